// Round 1
// baseline (50.193 us; speedup 1.0000x reference)
//
#include <hip/hip_runtime.h>
#include <hip/hip_bf16.h>

// Problem constants (from reference)
#define BATCH    1048576
#define NTILES   (BATCH / 16)     // 65536 wave-tiles of 16 rows
#define SCALE1   3.0f             // scale_factor + 1
#define CMIN    -10.0f
#define CMAX     10.0f

typedef __attribute__((ext_vector_type(8))) short  bf16x8;  // 8 bf16 = 4 VGPRs
typedef __attribute__((ext_vector_type(4))) float  f32x4;   // MFMA accumulator

__device__ __forceinline__ short f2bf(float f) {
    __hip_bfloat16 h = __float2bfloat16(f);   // RNE, lowers to v_cvt
    return __builtin_bit_cast(short, h);
}

// z = x @ W^T (bf16 MFMA), v = clamp(3z), lse = log(sum exp v), out = mish(lse)
__global__ __launch_bounds__(256, 4)
void fused_lse_mish(const float* __restrict__ x,
                    const float* __restrict__ W,
                    float* __restrict__ out) {
    // wave-private 2KB bf16 staging tiles (16 rows x 64 cols), 4 waves/block
    __shared__ alignas(16) unsigned char lds[4 * 2048];

    const int tid  = threadIdx.x;
    const int wid  = tid >> 6;
    const int lane = tid & 63;
    const int l15  = lane & 15;   // 0..15
    const int l4   = lane >> 4;   // 0..3
    unsigned char* wlds = lds + wid * 2048;

    // ---- Preload W^T fragments (held in registers for the whole kernel).
    // B-frag(t,s): lane holds B[k][n] with n = 16t + l15, k = 32s + 8*l4 + e
    // B[j][n] = W[n][j]  ->  W row (16t + l15), cols 32s + 8*l4 .. +7 (contiguous)
    bf16x8 bfrag[4][2];
    #pragma unroll
    for (int t = 0; t < 4; ++t) {
        const float* wp = W + (t * 16 + l15) * 64 + l4 * 8;
        #pragma unroll
        for (int s = 0; s < 2; ++s) {
            float4 w0 = *reinterpret_cast<const float4*>(wp + s * 32);
            float4 w1 = *reinterpret_cast<const float4*>(wp + s * 32 + 4);
            bf16x8 f;
            f[0] = f2bf(w0.x); f[1] = f2bf(w0.y); f[2] = f2bf(w0.z); f[3] = f2bf(w0.w);
            f[4] = f2bf(w1.x); f[5] = f2bf(w1.y); f[6] = f2bf(w1.z); f[7] = f2bf(w1.w);
            bfrag[t][s] = f;
        }
    }

    // LDS read addresses (A-frag: row = l15, k = 8*l4 + e per k-step)
    // swizzle: phys = row*128 + (col ^ ((row&7)<<4))  -- kills stride-128B conflicts
    const unsigned rswz = (unsigned)((l15 & 7) << 4);
    const unsigned ra0  = (unsigned)(l15 * 128) + (((unsigned)(l4 * 16))      ^ rswz);
    const unsigned ra1  = (unsigned)(l15 * 128) + (((unsigned)(64 + l4 * 16)) ^ rswz);

    const int gwave  = (int)((blockIdx.x * blockDim.x + tid) >> 6);
    const int nwaves = (int)((gridDim.x * blockDim.x) >> 6);

    for (int tile = gwave; tile < NTILES; tile += nwaves) {
        const float* xp = x + (size_t)tile * 16 * 64;

        // ---- stage 16 rows (fp32 -> bf16) into wave-private LDS, coalesced
        #pragma unroll
        for (int it = 0; it < 4; ++it) {
            const int r = it * 4 + l4;                       // row within tile
            float4 v = *reinterpret_cast<const float4*>(xp + r * 64 + l15 * 4);
            short4 b;
            b.x = f2bf(v.x); b.y = f2bf(v.y); b.z = f2bf(v.z); b.w = f2bf(v.w);
            unsigned wa = (unsigned)(r * 128) +
                          (((unsigned)(l15 * 8)) ^ ((unsigned)((r & 7) << 4)));
            *reinterpret_cast<short4*>(wlds + wa) = b;
        }
        // same-wave DS ops are in-order; no block barrier needed (wave-private tile)

        // ---- A fragments: 2x ds_read_b128
        bf16x8 a0 = *reinterpret_cast<const bf16x8*>(wlds + ra0);  // k 0..31
        bf16x8 a1 = *reinterpret_cast<const bf16x8*>(wlds + ra1);  // k 32..63

        // ---- 8 MFMAs: z[16][64] ; acc[t] covers hid cols 16t..16t+15
        f32x4 acc[4];
        #pragma unroll
        for (int t = 0; t < 4; ++t) {
            f32x4 z; z[0] = 0.f; z[1] = 0.f; z[2] = 0.f; z[3] = 0.f;
            z = __builtin_amdgcn_mfma_f32_16x16x32_bf16(a0, bfrag[t][0], z, 0, 0, 0);
            z = __builtin_amdgcn_mfma_f32_16x16x32_bf16(a1, bfrag[t][1], z, 0, 0, 0);
            acc[t] = z;
        }

        // ---- epilogue: C/D layout col = l15 (+16t), row = 4*l4 + i
        // v in [-10,10] -> exp-sum without max subtraction is safe in fp32
        float s[4];
        #pragma unroll
        for (int i = 0; i < 4; ++i) {
            float sum = 0.f;
            #pragma unroll
            for (int t = 0; t < 4; ++t) {
                float v = acc[t][i] * SCALE1;
                v = fminf(fmaxf(v, CMIN), CMAX);
                sum += __expf(v);
            }
            // reduce across the 16-lane group (rows 4*l4 + i live in lanes 16*l4..+15)
            sum += __shfl_xor(sum, 1);
            sum += __shfl_xor(sum, 2);
            sum += __shfl_xor(sum, 4);
            sum += __shfl_xor(sum, 8);
            s[i] = sum;
        }

        // lane 16*q + j (j<4) writes row 16*tile + 4*q + j
        float sv = (l15 == 0) ? s[0] : (l15 == 1) ? s[1] : (l15 == 2) ? s[2] : s[3];
        float lse = __logf(sv);
        float sp  = __logf(1.f + __expf(lse));          // softplus(lse)
        float e2  = __expf(2.f * sp);
        float th  = 1.f - 2.f / (e2 + 1.f);             // tanh(sp)
        float res = lse * th;
        if (l15 < 4) out[tile * 16 + l4 * 4 + l15] = res;
    }
}

extern "C" void kernel_launch(void* const* d_in, const int* in_sizes, int n_in,
                              void* d_out, int out_size, void* d_ws, size_t ws_size,
                              hipStream_t stream) {
    const float* x = (const float*)d_in[0];   // [BATCH, 64] fp32
    const float* W = (const float*)d_in[1];   // [64, 64]   fp32
    float* out = (float*)d_out;               // [BATCH] fp32 (B x 1)

    dim3 grid(2048), block(256);              // 8192 waves, 8 tiles/wave
    hipLaunchKernelGGL(fused_lse_mish, grid, block, 0, stream, x, W, out);
}